// Round 3
// baseline (286.807 us; speedup 1.0000x reference)
//
#include <hip/hip_runtime.h>
#include <math.h>

// Problem constants
#define BATCH   64
#define SAMP    32
#define SIGLEN  19530            // sum_{k=1..6} 5^k
#define NROWS   (BATCH * SAMP)   // 2048
#define NBISECT 40               // fp32 bisection on [0,2] fixed point after ~30 iters == 100
#define PER_T   8                // columns per thread in phase 2
#define TPR     2442             // ceil(SIGLEN / PER_T) threads per batch row
#define GX      39               // ceil(TPR / 64) wave-blocks per batch row

// Level boundaries (element index): level k occupies [LB[k-1], LB[k])
// LB = {0, 5, 30, 155, 780, 3905, 19530}

// Per-row weights (1/SAMP folded in). Fully rewritten each iteration by phase 1.
__device__ float g_pw[NROWS * 6];

__device__ __forceinline__ int level0(int l) {
    return (l >= 5) + (l >= 30) + (l >= 155) + (l >= 780) + (l >= 3905);
}

// ---------------------------------------------------------------------------
// Phase 1: one block per (b,s) row. Block reduction -> 6 per-level sums of
// x^2, bisection for the dilatation root, write w[m] = root^(m+1)/SAMP.
// float4 main body. Input is MALL-resident in steady state (fills are
// write-no-allocate), so this is issue/L3-bound, not HBM-bound.
// ---------------------------------------------------------------------------
__global__ __launch_bounds__(256) void es_phase1_kernel(const float* __restrict__ x) {
    const int r = blockIdx.x;                 // 0..2047
    const int t = threadIdx.x;
    const float* __restrict__ row = x + (size_t)r * SIGLEN;

    float a1 = 0.f, a2 = 0.f, a3 = 0.f, a4 = 0.f, a5 = 0.f, a6 = 0.f;

    // Levels 1..4: [0,155) static per-thread, [155,780) strided. 4% of bytes.
    if (t < 5)            { float v = row[t]; a1 += v * v; }
    else if (t < 30)      { float v = row[t]; a2 += v * v; }
    else if (t < 155)     { float v = row[t]; a3 += v * v; }
    for (int l = 155 + t; l < 780; l += 256) { float v = row[l]; a4 += v * v; }

    // Levels 5+6: [780,19530) = 18750 elems, float4 body.
    // Row base elem r*19530 % 4 == 2*(r&1): odd rows take a 2-elem head,
    // even rows a 2-elem tail; body is exactly 4687 aligned float4 either way.
    const int head = (r & 1) ? 2 : 0;
    if (head) { if (t == 0)  { float v0 = row[780],   v1 = row[781];   a5 += v0*v0 + v1*v1; } }
    else      { if (t == 32) { float v0 = row[19528], v1 = row[19529]; a6 += v0*v0 + v1*v1; } }

    const float4* __restrict__ p4 = (const float4*)(row + 780 + head);
    const int lb = 780 + head;
    #pragma unroll 4
    for (int q = t; q < 4687; q += 256) {
        const float4 v = p4[q];
        const int l = lb + 4 * q;                     // row-local elem index of v.x
        const float s = v.x*v.x + v.y*v.y + v.z*v.z + v.w*v.w;
        if (l >= 3905)      a6 += s;                  // pure level 6 (vast majority)
        else if (l <= 3901) a5 += s;                  // pure level 5
        else {                                        // the single straddling float4
            ((l     >= 3905) ? a6 : a5) += v.x * v.x;
            ((l + 1 >= 3905) ? a6 : a5) += v.y * v.y;
            ((l + 2 >= 3905) ? a6 : a5) += v.z * v.z;
            ((l + 3 >= 3905) ? a6 : a5) += v.w * v.w;
        }
    }

    // 64-lane butterfly, then cross-wave via LDS
    #pragma unroll
    for (int off = 32; off > 0; off >>= 1) {
        a1 += __shfl_xor(a1, off); a2 += __shfl_xor(a2, off);
        a3 += __shfl_xor(a3, off); a4 += __shfl_xor(a4, off);
        a5 += __shfl_xor(a5, off); a6 += __shfl_xor(a6, off);
    }
    __shared__ float red[4][6];
    const int wave = t >> 6, lane = t & 63;
    if (lane == 0) {
        red[wave][0] = a1; red[wave][1] = a2; red[wave][2] = a3;
        red[wave][3] = a4; red[wave][4] = a5; red[wave][5] = a6;
    }
    __syncthreads();

    if (t == 0) {
        float s1 = 0.f, s2 = 0.f, s3 = 0.f, s4 = 0.f, s5 = 0.f, s6 = 0.f;
        #pragma unroll
        for (int w = 0; w < 4; ++w) {
            s1 += red[w][0]; s2 += red[w][1]; s3 += red[w][2];
            s4 += red[w][3]; s5 += red[w][4]; s6 += red[w][5];
        }
        const float total = s1 + s2 + s3 + s4 + s5 + s6;
        const float nq  = 1.0f + total;
        // phi with C=4, a=1: x<=4 -> x ; else 4 + 16*(1/4 - 1/x) = 8 - 16/x
        const float phi = (nq > 4.0f) ? (8.0f - 16.0f / nq) : nq;
        const float c0  = 1.0f - phi;
        const bool  fin = isfinite(c0) && isfinite(total);

        float lo = 0.0f, hi = 2.0f;
        #pragma unroll 4
        for (int i = 0; i < NBISECT; ++i) {
            const float mid = 0.5f * (lo + hi);
            const float u = mid * mid;
            // poly(u) = c0 + s1 u + ... + s6 u^6 (Horner)
            const float pv = ((((((s6*u + s5)*u + s4)*u + s3)*u + s2)*u + s1)*u) + c0;
            const bool neg = pv < 0.0f;               // NaN -> false (matches jnp.where)
            lo = neg ? mid : lo;
            hi = neg ? hi : mid;
        }
        float root = 0.5f * (lo + hi);
        if (!fin) root = 0.0f;
        root = fminf(root, 1.0f);

        const float inv = 1.0f / SAMP;
        float w1 = root, w2 = w1*root, w3 = w2*root, w4 = w3*root, w5 = w4*root, w6 = w5*root;
        float* dst = g_pw + (size_t)r * 6;
        dst[0] = w1 * inv; dst[1] = w2 * inv; dst[2] = w3 * inv;
        dst[3] = w4 * inv; dst[4] = w5 * inv; dst[5] = w6 * inv;
    }
}

// ---------------------------------------------------------------------------
// Phase 2: out[b,l] = sum_s x[b,s,l] * w[b,s][level(l)]  (1/32 pre-folded).
// 8 columns per thread. Per-s row parity alternates (base elem = 2*(s&1) mod 4):
//   even s: 2x aligned float4 (2 VMEM / 32 B)
//   odd  s: float2 + aligned float4 + float2 (3 VMEM / 32 B)
// avg 2.5 VMEM/32B vs 4 for the old float2 scheme -> -39% VMEM issue.
// Single-wave blocks, grid (GX, BATCH) = 2496 blocks (~10 waves/CU).
// Kernel boundary (same stream) orders g_pw writes -> reads.
// ---------------------------------------------------------------------------
__global__ __launch_bounds__(64) void es_phase2_kernel(const float* __restrict__ x,
                                                       float* __restrict__ out) {
    const int b = blockIdx.y;
    const int t = threadIdx.x;

    __shared__ float wsh[SAMP * 6];   // [s*6 + lev]
    for (int i = t; i < SAMP * 6; i += 64)
        wsh[i] = g_pw[(size_t)b * (SAMP * 6) + i];
    __syncthreads();                  // single wave: compiles to lgkmcnt wait

    const int idx = blockIdx.x * 64 + t;
    if (idx >= TPR) return;
    const int l0 = idx * PER_T;                 // first column (multiple of 8)
    const int ncol = min(PER_T, SIGLEN - l0);   // 8 except the final thread (2)

    // Per-column level. Window spans at most one boundary (gaps > 8).
    int lev[PER_T];
    #pragma unroll
    for (int c = 0; c < PER_T; ++c) lev[c] = level0(min(l0 + c, SIGLEN - 1));
    const bool uni = (lev[0] == lev[PER_T - 1]) & (ncol == PER_T);

    float acc[PER_T];
    #pragma unroll
    for (int c = 0; c < PER_T; ++c) acc[c] = 0.f;

    const float* __restrict__ xb = x + (size_t)b * (SAMP * (size_t)SIGLEN) + l0;

    if (uni) {                                  // fast path: all but ~6 threads per b
        const int lv = lev[0];
        #pragma unroll 8
        for (int s = 0; s < SAMP; ++s) {
            const float ws = wsh[s * 6 + lv];   // wave-broadcast LDS read
            const float* rp = xb + (size_t)s * SIGLEN;
            float v0, v1, v2, v3, v4, v5, v6, v7;
            if ((s & 1) == 0) {                 // row elem base % 4 == 0
                const float4 qa = *(const float4*)rp;
                const float4 qb = *(const float4*)(rp + 4);
                v0 = qa.x; v1 = qa.y; v2 = qa.z; v3 = qa.w;
                v4 = qb.x; v5 = qb.y; v6 = qb.z; v7 = qb.w;
            } else {                            // row elem base % 4 == 2
                const float2 h  = *(const float2*)rp;
                const float4 m  = *(const float4*)(rp + 2);
                const float2 tl = *(const float2*)(rp + 6);
                v0 = h.x;  v1 = h.y;  v2 = m.x;  v3 = m.y;
                v4 = m.z;  v5 = m.w;  v6 = tl.x; v7 = tl.y;
            }
            acc[0] += v0 * ws; acc[1] += v1 * ws; acc[2] += v2 * ws; acc[3] += v3 * ws;
            acc[4] += v4 * ws; acc[5] += v5 * ws; acc[6] += v6 * ws; acc[7] += v7 * ws;
        }
    } else {                                    // boundary straddle / tail: scalar
        for (int s = 0; s < SAMP; ++s) {
            const float* rp = xb + (size_t)s * SIGLEN;
            for (int c = 0; c < ncol; ++c)
                acc[c] += rp[c] * wsh[s * 6 + lev[c]];
        }
    }

    float* op = out + (size_t)b * SIGLEN + l0;  // elem base % 4 == 2*(b&1)
    if (ncol == PER_T) {
        if ((b & 1) == 0) {
            *(float4*)op       = make_float4(acc[0], acc[1], acc[2], acc[3]);
            *(float4*)(op + 4) = make_float4(acc[4], acc[5], acc[6], acc[7]);
        } else {
            *(float2*)op       = make_float2(acc[0], acc[1]);
            *(float4*)(op + 2) = make_float4(acc[2], acc[3], acc[4], acc[5]);
            *(float2*)(op + 6) = make_float2(acc[6], acc[7]);
        }
    } else {
        for (int c = 0; c < ncol; ++c) op[c] = acc[c];
    }
}

extern "C" void kernel_launch(void* const* d_in, const int* in_sizes, int n_in,
                              void* d_out, int out_size, void* d_ws, size_t ws_size,
                              hipStream_t stream) {
    const float* x = (const float*)d_in[0];   // [64,32,19530] fp32
    float* out = (float*)d_out;               // [64,19530] fp32
    (void)d_ws; (void)ws_size;                // workspace unused

    es_phase1_kernel<<<NROWS, 256, 0, stream>>>(x);
    dim3 gridB(GX, BATCH);
    es_phase2_kernel<<<gridB, 64, 0, stream>>>(x, out);
}

// Round 4
// 251.360 us; speedup vs baseline: 1.1410x; 1.1410x over previous
//
#include <hip/hip_runtime.h>
#include <math.h>

// Problem constants
#define BATCH   64
#define SAMP    32
#define SIGLEN  19530            // sum_{k=1..6} 5^k
#define NROWS   (BATCH * SAMP)   // 2048
#define NBISECT 40               // fp32 bisection on [0,2] fixed point after ~30 iters == 100
#define P2COLS  1024             // columns per phase-2 block (256 threads x 4)
#define P2GX    20               // ceil(SIGLEN / P2COLS); last chunk = 74 cols

// Level boundaries (element index): level k occupies [LB[k-1], LB[k])
// LB = {0, 5, 30, 155, 780, 3905, 19530}

// Per-row weights (1/SAMP folded in). Fully rewritten each iteration by phase 1.
__device__ float g_pw[NROWS * 6];

__device__ __forceinline__ int level0(int l) {
    return (l >= 5) + (l >= 30) + (l >= 155) + (l >= 780) + (l >= 3905);
}

// ---------------------------------------------------------------------------
// Phase 1: one block per (b,s) row. Block reduction -> 6 per-level sums of
// x^2, bisection for the dilatation root, write w[m] = root^(m+1)/SAMP.
// float4 main body; fully coalesced. (unchanged, known-good)
// ---------------------------------------------------------------------------
__global__ __launch_bounds__(256) void es_phase1_kernel(const float* __restrict__ x) {
    const int r = blockIdx.x;                 // 0..2047
    const int t = threadIdx.x;
    const float* __restrict__ row = x + (size_t)r * SIGLEN;

    float a1 = 0.f, a2 = 0.f, a3 = 0.f, a4 = 0.f, a5 = 0.f, a6 = 0.f;

    if (t < 5)            { float v = row[t]; a1 += v * v; }
    else if (t < 30)      { float v = row[t]; a2 += v * v; }
    else if (t < 155)     { float v = row[t]; a3 += v * v; }
    for (int l = 155 + t; l < 780; l += 256) { float v = row[l]; a4 += v * v; }

    // Levels 5+6: [780,19530). Row base elem r*19530 % 4 == 2*(r&1).
    const int head = (r & 1) ? 2 : 0;
    if (head) { if (t == 0)  { float v0 = row[780],   v1 = row[781];   a5 += v0*v0 + v1*v1; } }
    else      { if (t == 32) { float v0 = row[19528], v1 = row[19529]; a6 += v0*v0 + v1*v1; } }

    const float4* __restrict__ p4 = (const float4*)(row + 780 + head);
    const int lb = 780 + head;
    #pragma unroll 4
    for (int q = t; q < 4687; q += 256) {
        const float4 v = p4[q];
        const int l = lb + 4 * q;
        const float s = v.x*v.x + v.y*v.y + v.z*v.z + v.w*v.w;
        if (l >= 3905)      a6 += s;
        else if (l <= 3901) a5 += s;
        else {
            ((l     >= 3905) ? a6 : a5) += v.x * v.x;
            ((l + 1 >= 3905) ? a6 : a5) += v.y * v.y;
            ((l + 2 >= 3905) ? a6 : a5) += v.z * v.z;
            ((l + 3 >= 3905) ? a6 : a5) += v.w * v.w;
        }
    }

    #pragma unroll
    for (int off = 32; off > 0; off >>= 1) {
        a1 += __shfl_xor(a1, off); a2 += __shfl_xor(a2, off);
        a3 += __shfl_xor(a3, off); a4 += __shfl_xor(a4, off);
        a5 += __shfl_xor(a5, off); a6 += __shfl_xor(a6, off);
    }
    __shared__ float red[4][6];
    const int wave = t >> 6, lane = t & 63;
    if (lane == 0) {
        red[wave][0] = a1; red[wave][1] = a2; red[wave][2] = a3;
        red[wave][3] = a4; red[wave][4] = a5; red[wave][5] = a6;
    }
    __syncthreads();

    if (t == 0) {
        float s1 = 0.f, s2 = 0.f, s3 = 0.f, s4 = 0.f, s5 = 0.f, s6 = 0.f;
        #pragma unroll
        for (int w = 0; w < 4; ++w) {
            s1 += red[w][0]; s2 += red[w][1]; s3 += red[w][2];
            s4 += red[w][3]; s5 += red[w][4]; s6 += red[w][5];
        }
        const float total = s1 + s2 + s3 + s4 + s5 + s6;
        const float nq  = 1.0f + total;
        const float phi = (nq > 4.0f) ? (8.0f - 16.0f / nq) : nq;  // C=4,a=1
        const float c0  = 1.0f - phi;
        const bool  fin = isfinite(c0) && isfinite(total);

        float lo = 0.0f, hi = 2.0f;
        #pragma unroll 4
        for (int i = 0; i < NBISECT; ++i) {
            const float mid = 0.5f * (lo + hi);
            const float u = mid * mid;
            const float pv = ((((((s6*u + s5)*u + s4)*u + s3)*u + s2)*u + s1)*u) + c0;
            const bool neg = pv < 0.0f;               // NaN -> false (matches jnp.where)
            lo = neg ? mid : lo;
            hi = neg ? hi : mid;
        }
        float root = 0.5f * (lo + hi);
        if (!fin) root = 0.0f;
        root = fminf(root, 1.0f);

        const float inv = 1.0f / SAMP;
        float w1 = root, w2 = w1*root, w3 = w2*root, w4 = w3*root, w5 = w4*root, w6 = w5*root;
        float* dst = g_pw + (size_t)r * 6;
        dst[0] = w1 * inv; dst[1] = w2 * inv; dst[2] = w3 * inv;
        dst[3] = w4 * inv; dst[4] = w5 * inv; dst[5] = w6 * inv;
    }
}

// ---------------------------------------------------------------------------
// Phase 2: out[b,l] = sum_s x[b,s,l] * w[b,s][level(l)]  (1/32 pre-folded).
// Thread t owns cols [c0+4t, c0+4t+4): lane-adjacent float4 loads are
// CONTIGUOUS (1KB/wave/instr). Per-sample parity (odd rows 8-mod-16 aligned)
// handled by shifting the odd-sample window +2 cols (16B-aligned there) into
// a parity-split accumulator; one shfl_up + LDS handoff realigns after the
// loop. 1 dwordx4 per sample per 4 cols -> 10.2M VMEM (half of float2 scheme).
// Grid (P2GX, BATCH), block 256 (20 waves/CU). Tail chunk (74 cols) scalar.
// ---------------------------------------------------------------------------
__global__ __launch_bounds__(256) void es_phase2_kernel(const float* __restrict__ x,
                                                        float* __restrict__ out) {
    const int b  = blockIdx.y;
    const int k  = blockIdx.x;
    const int t  = threadIdx.x;
    const int c0 = k * P2COLS;

    __shared__ float wsh[SAMP * 6];   // [s*6 + lev]
    __shared__ float xw[3][2];        // cross-wave handoff of ao2/ao3
    if (t < SAMP * 6) wsh[t] = g_pw[(size_t)b * (SAMP * 6) + t];
    __syncthreads();

    const float* __restrict__ xb = x + (size_t)b * (SAMP * (size_t)SIGLEN);

    if (c0 + P2COLS > SIGLEN) {                 // tail chunk: 74 cols, scalar
        const int col = c0 + t;
        if (col < SIGLEN) {
            const int lv = level0(col);
            float acc = 0.f;
            #pragma unroll 8
            for (int s = 0; s < SAMP; ++s)
                acc += xb[(size_t)s * SIGLEN + col] * wsh[s * 6 + lv];
            out[(size_t)b * SIGLEN + col] = acc;
        }
        return;                                  // uniform for whole block
    }

    const int col = c0 + 4 * t;                  // multiple of 4
    // even rows (base%4==0): float4 at col      -> cols col..col+3
    // odd  rows (base%4==2): float4 at col+2    -> cols col+2..col+5 (16B-aligned)
    float ae0=0.f, ae1=0.f, ae2=0.f, ae3=0.f;    // even-parity partials, cols col+0..3
    float ao0=0.f, ao1=0.f, ao2=0.f, ao3=0.f;    // odd-parity partials, cols col+2..5
    float ah0=0.f, ah1=0.f;                      // t==0 only: odd partials, cols c0,c0+1

    const float* __restrict__ pe = xb + col;
    const float* __restrict__ po = xb + col + 2;

    const int lA = level0(col), lB = level0(col + 5);
    if (lA == lB) {                              // uniform level (all but ~6 threads/chunk)
        #pragma unroll
        for (int sp = 0; sp < 16; ++sp) {
            const int se = 2 * sp, so = 2 * sp + 1;
            const float4 ve = *(const float4*)(pe + (size_t)se * SIGLEN);
            const float4 vo = *(const float4*)(po + (size_t)so * SIGLEN);
            const float we = wsh[se * 6 + lA];
            const float wo = wsh[so * 6 + lA];
            ae0 += ve.x * we; ae1 += ve.y * we; ae2 += ve.z * we; ae3 += ve.w * we;
            ao0 += vo.x * wo; ao1 += vo.y * wo; ao2 += vo.z * wo; ao3 += vo.w * wo;
        }
    } else {                                     // level-boundary window: per-col weights
        const int le0 = level0(col),     le1 = level0(col + 1);
        const int le2 = level0(col + 2), le3 = level0(col + 3);
        const int lo2 = level0(col + 4), lo3 = level0(col + 5);
        #pragma unroll 4
        for (int sp = 0; sp < 16; ++sp) {
            const int se = 2 * sp, so = 2 * sp + 1;
            const float4 ve = *(const float4*)(pe + (size_t)se * SIGLEN);
            const float4 vo = *(const float4*)(po + (size_t)so * SIGLEN);
            ae0 += ve.x * wsh[se*6 + le0]; ae1 += ve.y * wsh[se*6 + le1];
            ae2 += ve.z * wsh[se*6 + le2]; ae3 += ve.w * wsh[se*6 + le3];
            ao0 += vo.x * wsh[so*6 + le2]; ao1 += vo.y * wsh[so*6 + le3];
            ao2 += vo.z * wsh[so*6 + lo2]; ao3 += vo.w * wsh[so*6 + lo3];
        }
    }

    if (t == 0) {                                // head: odd-parity cols c0, c0+1
        const int lh0 = level0(c0), lh1 = level0(c0 + 1);
        #pragma unroll
        for (int so = 1; so < SAMP; so += 2) {
            const float2 vh = *(const float2*)(xb + (size_t)so * SIGLEN + c0);
            ah0 += vh.x * wsh[so * 6 + lh0];
            ah1 += vh.y * wsh[so * 6 + lh1];
        }
    }

    // Realign odd partials: thread t's cols col,col+1 odd parts live in t-1's ao2,ao3.
    float po2 = __shfl_up(ao2, 1);               // valid within wave for lane>0
    float po3 = __shfl_up(ao3, 1);
    const int wave = t >> 6, lane = t & 63;
    if (lane == 63 && wave < 3) { xw[wave][0] = ao2; xw[wave][1] = ao3; }
    __syncthreads();
    if (lane == 0) {
        if (wave > 0) { po2 = xw[wave - 1][0]; po3 = xw[wave - 1][1]; }
        else          { po2 = ah0;             po3 = ah1;             }  // t==0
    }
    // (last thread's ao2/ao3 cover next chunk's first 2 cols -> discarded; that
    //  chunk's own head-float2 supplies them)

    const float f0 = ae0 + po2, f1 = ae1 + po3;
    const float f2 = ae2 + ao0, f3 = ae3 + ao1;

    float* op = out + (size_t)b * SIGLEN + col;  // elem base % 4 == 2*(b&1)
    if ((b & 1) == 0) {
        *(float4*)op = make_float4(f0, f1, f2, f3);
    } else {
        *(float2*)op       = make_float2(f0, f1);
        *(float2*)(op + 2) = make_float2(f2, f3);
    }
}

extern "C" void kernel_launch(void* const* d_in, const int* in_sizes, int n_in,
                              void* d_out, int out_size, void* d_ws, size_t ws_size,
                              hipStream_t stream) {
    const float* x = (const float*)d_in[0];   // [64,32,19530] fp32
    float* out = (float*)d_out;               // [64,19530] fp32
    (void)d_ws; (void)ws_size;                // workspace unused

    es_phase1_kernel<<<NROWS, 256, 0, stream>>>(x);
    dim3 gridB(P2GX, BATCH);
    es_phase2_kernel<<<gridB, 256, 0, stream>>>(x, out);
}

// Round 5
// 249.960 us; speedup vs baseline: 1.1474x; 1.0056x over previous
//
#include <hip/hip_runtime.h>
#include <math.h>

// Problem constants
#define BATCH   64
#define SAMP    32
#define SIGLEN  19530            // sum_{k=1..6} 5^k
#define NROWS   (BATCH * SAMP)   // 2048
#define NBISECT 40               // fp32 bisection on [0,2] fixed point after ~30 iters == 100
#define P2COLS  1024             // columns per phase-2 block (256 threads x 4)
#define P2GX    20               // ceil(SIGLEN / P2COLS); last chunk = 74 cols

// Level boundaries (element index): level k occupies [LB[k-1], LB[k])
// LB = {0, 5, 30, 155, 780, 3905, 19530}

// Per-row weights (1/SAMP folded in). Fully rewritten each iteration by phase 1.
__device__ float g_pw[NROWS * 6];

__device__ __forceinline__ int level0(int l) {
    return (l >= 5) + (l >= 30) + (l >= 155) + (l >= 780) + (l >= 3905);
}

// ---------------------------------------------------------------------------
// Phase 1: one block per (b,s) row. Block reduction -> 6 per-level sums of
// x^2, bisection for the dilatation root, write w[m] = root^(m+1)/SAMP.
// Split level-5 / level-6 float4 loops: no per-iteration level tests in the
// hot body. __launch_bounds__(256,8) forces VGPR<=64 -> 8 blocks/CU (32
// waves/CU) for latency hiding of the L3-resident stream.
// ---------------------------------------------------------------------------
__global__ __launch_bounds__(256, 8) void es_phase1_kernel(const float* __restrict__ x) {
    const int r = blockIdx.x;                 // 0..2047
    const int t = threadIdx.x;
    const float* __restrict__ row = x + (size_t)r * SIGLEN;

    float a1 = 0.f, a2 = 0.f, a3 = 0.f, a4 = 0.f, a5 = 0.f, a6 = 0.f;

    // Levels 1..4: [0,155) static per-thread, [155,780) strided. 4% of bytes.
    if (t < 5)            { float v = row[t]; a1 += v * v; }
    else if (t < 30)      { float v = row[t]; a2 += v * v; }
    else if (t < 155)     { float v = row[t]; a3 += v * v; }
    for (int l = 155 + t; l < 780; l += 256) { float v = row[l]; a4 += v * v; }

    // Levels 5+6: [780,19530). Global row base elem r*19530 % 4 == 2*(r&1).
    //  even r: f4 level-5 span [780,3904)  (781 f4), straddle {3904..3907},
    //          f4 level-6 span [3908,19528) (3905 f4), tail {19528,19529}
    //  odd  r: head {780,781}, f4 level-5 span [782,3902) (780 f4),
    //          straddle {3902..3905}, f4 level-6 span [3906,19530) (3906 f4)
    const int head = (r & 1) ? 2 : 0;
    if (head) {
        if (t == 0)  { float v0 = row[780],  v1 = row[781];
                       a5 += v0*v0 + v1*v1; }
        if (t == 64) { float u0 = row[3902], u1 = row[3903], u2 = row[3904], u3 = row[3905];
                       a5 += u0*u0 + u1*u1 + u2*u2; a6 += u3*u3; }
    } else {
        if (t == 0)  { float v0 = row[19528], v1 = row[19529];
                       a6 += v0*v0 + v1*v1; }
        if (t == 64) { float u0 = row[3904], u1 = row[3905], u2 = row[3906], u3 = row[3907];
                       a5 += u0*u0; a6 += u1*u1 + u2*u2 + u3*u3; }
    }

    const float4* __restrict__ pA = (const float4*)(row + 780 + head);          // 16B-aligned
    const float4* __restrict__ pB = (const float4*)(row + (head ? 3906 : 3908)); // 16B-aligned
    const int Q5 = head ? 780 : 781;
    const int Q6 = head ? 3906 : 3905;

    #pragma unroll 2
    for (int q = t; q < Q5; q += 256) {
        const float4 v = pA[q];
        a5 += v.x*v.x + v.y*v.y + v.z*v.z + v.w*v.w;
    }
    #pragma unroll 4
    for (int q = t; q < Q6; q += 256) {
        const float4 v = pB[q];
        a6 += v.x*v.x + v.y*v.y + v.z*v.z + v.w*v.w;
    }

    // 64-lane butterfly, then cross-wave via LDS
    #pragma unroll
    for (int off = 32; off > 0; off >>= 1) {
        a1 += __shfl_xor(a1, off); a2 += __shfl_xor(a2, off);
        a3 += __shfl_xor(a3, off); a4 += __shfl_xor(a4, off);
        a5 += __shfl_xor(a5, off); a6 += __shfl_xor(a6, off);
    }
    __shared__ float red[4][6];
    const int wave = t >> 6, lane = t & 63;
    if (lane == 0) {
        red[wave][0] = a1; red[wave][1] = a2; red[wave][2] = a3;
        red[wave][3] = a4; red[wave][4] = a5; red[wave][5] = a6;
    }
    __syncthreads();

    if (t == 0) {
        float s1 = 0.f, s2 = 0.f, s3 = 0.f, s4 = 0.f, s5 = 0.f, s6 = 0.f;
        #pragma unroll
        for (int w = 0; w < 4; ++w) {
            s1 += red[w][0]; s2 += red[w][1]; s3 += red[w][2];
            s4 += red[w][3]; s5 += red[w][4]; s6 += red[w][5];
        }
        const float total = s1 + s2 + s3 + s4 + s5 + s6;
        const float nq  = 1.0f + total;
        const float phi = (nq > 4.0f) ? (8.0f - 16.0f / nq) : nq;  // C=4,a=1
        const float c0  = 1.0f - phi;
        const bool  fin = isfinite(c0) && isfinite(total);

        float lo = 0.0f, hi = 2.0f;
        #pragma unroll 4
        for (int i = 0; i < NBISECT; ++i) {
            const float mid = 0.5f * (lo + hi);
            const float u = mid * mid;
            const float pv = ((((((s6*u + s5)*u + s4)*u + s3)*u + s2)*u + s1)*u) + c0;
            const bool neg = pv < 0.0f;               // NaN -> false (matches jnp.where)
            lo = neg ? mid : lo;
            hi = neg ? hi : mid;
        }
        float root = 0.5f * (lo + hi);
        if (!fin) root = 0.0f;
        root = fminf(root, 1.0f);

        const float inv = 1.0f / SAMP;
        float w1 = root, w2 = w1*root, w3 = w2*root, w4 = w3*root, w5 = w4*root, w6 = w5*root;
        float* dst = g_pw + (size_t)r * 6;
        dst[0] = w1 * inv; dst[1] = w2 * inv; dst[2] = w3 * inv;
        dst[3] = w4 * inv; dst[4] = w5 * inv; dst[5] = w6 * inv;
    }
}

// ---------------------------------------------------------------------------
// Phase 2: out[b,l] = sum_s x[b,s,l] * w[b,s][level(l)]  (1/32 pre-folded).
// Thread t owns cols [c0+4t, c0+4t+4): lane-adjacent float4 loads are
// CONTIGUOUS (1KB/wave/instr). Per-sample parity handled by shifting the
// odd-sample window +2 cols into a parity-split accumulator; one shfl_up +
// LDS handoff realigns after the loop. Batch order REVERSED (bb = 63-y) so
// the first-dispatched blocks hit phase-1's L2 tail (~32MB partial reuse).
// __launch_bounds__(256,5): VGPR<=102, grid supplies 5 blocks/CU (20 waves).
// ---------------------------------------------------------------------------
__global__ __launch_bounds__(256, 5) void es_phase2_kernel(const float* __restrict__ x,
                                                           float* __restrict__ out) {
    const int bb = (BATCH - 1) - blockIdx.y;    // reversed batch index
    const int k  = blockIdx.x;
    const int t  = threadIdx.x;
    const int c0 = k * P2COLS;

    __shared__ float wsh[SAMP * 6];   // [s*6 + lev]
    __shared__ float xw[3][2];        // cross-wave handoff of ao2/ao3
    if (t < SAMP * 6) wsh[t] = g_pw[(size_t)bb * (SAMP * 6) + t];
    __syncthreads();

    const float* __restrict__ xb = x + (size_t)bb * (SAMP * (size_t)SIGLEN);

    if (c0 + P2COLS > SIGLEN) {                 // tail chunk: 74 cols, scalar
        const int col = c0 + t;
        if (col < SIGLEN) {
            const int lv = level0(col);
            float acc = 0.f;
            #pragma unroll 8
            for (int s = 0; s < SAMP; ++s)
                acc += xb[(size_t)s * SIGLEN + col] * wsh[s * 6 + lv];
            out[(size_t)bb * SIGLEN + col] = acc;
        }
        return;                                  // uniform for whole block
    }

    const int col = c0 + 4 * t;                  // multiple of 4
    // even rows (base%4==0): float4 at col      -> cols col..col+3
    // odd  rows (base%4==2): float4 at col+2    -> cols col+2..col+5 (16B-aligned)
    float ae0=0.f, ae1=0.f, ae2=0.f, ae3=0.f;    // even-parity partials, cols col+0..3
    float ao0=0.f, ao1=0.f, ao2=0.f, ao3=0.f;    // odd-parity partials, cols col+2..5
    float ah0=0.f, ah1=0.f;                      // t==0 only: odd partials, cols c0,c0+1

    const float* __restrict__ pe = xb + col;
    const float* __restrict__ po = xb + col + 2;

    const int lA = level0(col), lB = level0(col + 5);
    if (lA == lB) {                              // uniform level (all but ~6 threads/chunk)
        #pragma unroll
        for (int sp = 0; sp < 16; ++sp) {
            const int se = 2 * sp, so = 2 * sp + 1;
            const float4 ve = *(const float4*)(pe + (size_t)se * SIGLEN);
            const float4 vo = *(const float4*)(po + (size_t)so * SIGLEN);
            const float we = wsh[se * 6 + lA];
            const float wo = wsh[so * 6 + lA];
            ae0 += ve.x * we; ae1 += ve.y * we; ae2 += ve.z * we; ae3 += ve.w * we;
            ao0 += vo.x * wo; ao1 += vo.y * wo; ao2 += vo.z * wo; ao3 += vo.w * wo;
        }
    } else {                                     // level-boundary window: per-col weights
        const int le0 = level0(col),     le1 = level0(col + 1);
        const int le2 = level0(col + 2), le3 = level0(col + 3);
        const int lo2 = level0(col + 4), lo3 = level0(col + 5);
        #pragma unroll 4
        for (int sp = 0; sp < 16; ++sp) {
            const int se = 2 * sp, so = 2 * sp + 1;
            const float4 ve = *(const float4*)(pe + (size_t)se * SIGLEN);
            const float4 vo = *(const float4*)(po + (size_t)so * SIGLEN);
            ae0 += ve.x * wsh[se*6 + le0]; ae1 += ve.y * wsh[se*6 + le1];
            ae2 += ve.z * wsh[se*6 + le2]; ae3 += ve.w * wsh[se*6 + le3];
            ao0 += vo.x * wsh[so*6 + le2]; ao1 += vo.y * wsh[so*6 + le3];
            ao2 += vo.z * wsh[so*6 + lo2]; ao3 += vo.w * wsh[so*6 + lo3];
        }
    }

    if (t == 0) {                                // head: odd-parity cols c0, c0+1
        const int lh0 = level0(c0), lh1 = level0(c0 + 1);
        #pragma unroll
        for (int so = 1; so < SAMP; so += 2) {
            const float2 vh = *(const float2*)(xb + (size_t)so * SIGLEN + c0);
            ah0 += vh.x * wsh[so * 6 + lh0];
            ah1 += vh.y * wsh[so * 6 + lh1];
        }
    }

    // Realign odd partials: thread t's cols col,col+1 odd parts live in t-1's ao2,ao3.
    float po2 = __shfl_up(ao2, 1);               // valid within wave for lane>0
    float po3 = __shfl_up(ao3, 1);
    const int wave = t >> 6, lane = t & 63;
    if (lane == 63 && wave < 3) { xw[wave][0] = ao2; xw[wave][1] = ao3; }
    __syncthreads();
    if (lane == 0) {
        if (wave > 0) { po2 = xw[wave - 1][0]; po3 = xw[wave - 1][1]; }
        else          { po2 = ah0;             po3 = ah1;             }  // t==0
    }
    // (last thread's ao2/ao3 cover next chunk's first 2 cols -> discarded; that
    //  chunk's own head-float2 supplies them)

    const float f0 = ae0 + po2, f1 = ae1 + po3;
    const float f2 = ae2 + ao0, f3 = ae3 + ao1;

    float* op = out + (size_t)bb * SIGLEN + col; // elem base % 4 == 2*(bb&1)
    if ((bb & 1) == 0) {
        *(float4*)op = make_float4(f0, f1, f2, f3);
    } else {
        *(float2*)op       = make_float2(f0, f1);
        *(float2*)(op + 2) = make_float2(f2, f3);
    }
}

extern "C" void kernel_launch(void* const* d_in, const int* in_sizes, int n_in,
                              void* d_out, int out_size, void* d_ws, size_t ws_size,
                              hipStream_t stream) {
    const float* x = (const float*)d_in[0];   // [64,32,19530] fp32
    float* out = (float*)d_out;               // [64,19530] fp32
    (void)d_ws; (void)ws_size;                // workspace unused

    es_phase1_kernel<<<NROWS, 256, 0, stream>>>(x);
    dim3 gridB(P2GX, BATCH);
    es_phase2_kernel<<<gridB, 256, 0, stream>>>(x, out);
}

// Round 7
// 246.893 us; speedup vs baseline: 1.1617x; 1.0124x over previous
//
#include <hip/hip_runtime.h>
#include <math.h>

// Problem constants
#define BATCH   64
#define SAMP    32
#define SIGLEN  19530            // sum_{k=1..6} 5^k
#define NROWS   (BATCH * SAMP)   // 2048
#define NBISECT 40               // fp32 bisection on [0,2] fixed point after ~30 iters == 100
#define P2COLS  1024             // columns per phase-2 block (256 threads x 4)
#define P2GX    20               // ceil(SIGLEN / P2COLS); last chunk = 74 cols

// Level boundaries (element index): level k occupies [LB[k-1], LB[k])
// LB = {0, 5, 30, 155, 780, 3905, 19530}

// NT-capable vector types (clang ext_vector works with __builtin_nontemporal_load)
typedef float f32x4 __attribute__((ext_vector_type(4)));
typedef float f32x2 __attribute__((ext_vector_type(2)));

// Per-row weights (1/SAMP folded in). Fully rewritten each iteration by phase 1;
// kernel boundary on the same stream orders writes -> reads (r2-r5 proven).
__device__ float g_pw[NROWS * 6];

__device__ __forceinline__ int level0(int l) {
    return (l >= 5) + (l >= 30) + (l >= 155) + (l >= 780) + (l >= 3905);
}

// ---------------------------------------------------------------------------
// Phase 1: one block per (b,s) row. Block reduction -> 6 per-level sums of
// x^2, bisection for the dilatation root, write w[m] = root^(m+1)/SAMP.
// Split level-5/level-6 float4 loops; hot loads NON-TEMPORAL (zero reuse
// within the kernel -> skip L2 allocation, relieve TCC alloc/evict churn).
// ---------------------------------------------------------------------------
__global__ __launch_bounds__(256, 8) void es_phase1_kernel(const float* __restrict__ x) {
    const int r = blockIdx.x;                 // 0..2047
    const int t = threadIdx.x;
    const float* __restrict__ row = x + (size_t)r * SIGLEN;

    float a1 = 0.f, a2 = 0.f, a3 = 0.f, a4 = 0.f, a5 = 0.f, a6 = 0.f;

    // Levels 1..4: [0,155) static per-thread, [155,780) strided. 4% of bytes.
    if (t < 5)            { float v = row[t]; a1 += v * v; }
    else if (t < 30)      { float v = row[t]; a2 += v * v; }
    else if (t < 155)     { float v = row[t]; a3 += v * v; }
    for (int l = 155 + t; l < 780; l += 256) { float v = row[l]; a4 += v * v; }

    // Levels 5+6: [780,19530). Global row base elem r*19530 % 4 == 2*(r&1).
    //  even r: f4 L5 span [780,3904) (781 f4), straddle {3904..3907},
    //          f4 L6 span [3908,19528) (3905 f4), tail {19528,19529}
    //  odd  r: head {780,781}, f4 L5 span [782,3902) (780 f4),
    //          straddle {3902..3905}, f4 L6 span [3906,19530) (3906 f4)
    const int head = (r & 1) ? 2 : 0;
    if (head) {
        if (t == 0)  { float v0 = row[780],  v1 = row[781];
                       a5 += v0*v0 + v1*v1; }
        if (t == 64) { float u0 = row[3902], u1 = row[3903], u2 = row[3904], u3 = row[3905];
                       a5 += u0*u0 + u1*u1 + u2*u2; a6 += u3*u3; }
    } else {
        if (t == 0)  { float v0 = row[19528], v1 = row[19529];
                       a6 += v0*v0 + v1*v1; }
        if (t == 64) { float u0 = row[3904], u1 = row[3905], u2 = row[3906], u3 = row[3907];
                       a5 += u0*u0; a6 += u1*u1 + u2*u2 + u3*u3; }
    }

    const f32x4* __restrict__ pA = (const f32x4*)(row + 780 + head);           // 16B-aligned
    const f32x4* __restrict__ pB = (const f32x4*)(row + (head ? 3906 : 3908)); // 16B-aligned
    const int Q5 = head ? 780 : 781;
    const int Q6 = head ? 3906 : 3905;

    #pragma unroll 2
    for (int q = t; q < Q5; q += 256) {
        const f32x4 v = __builtin_nontemporal_load(pA + q);
        a5 += v.x*v.x + v.y*v.y + v.z*v.z + v.w*v.w;
    }
    #pragma unroll 4
    for (int q = t; q < Q6; q += 256) {
        const f32x4 v = __builtin_nontemporal_load(pB + q);
        a6 += v.x*v.x + v.y*v.y + v.z*v.z + v.w*v.w;
    }

    // 64-lane butterfly, then cross-wave via LDS
    #pragma unroll
    for (int off = 32; off > 0; off >>= 1) {
        a1 += __shfl_xor(a1, off); a2 += __shfl_xor(a2, off);
        a3 += __shfl_xor(a3, off); a4 += __shfl_xor(a4, off);
        a5 += __shfl_xor(a5, off); a6 += __shfl_xor(a6, off);
    }
    __shared__ float red[4][6];
    const int wave = t >> 6, lane = t & 63;
    if (lane == 0) {
        red[wave][0] = a1; red[wave][1] = a2; red[wave][2] = a3;
        red[wave][3] = a4; red[wave][4] = a5; red[wave][5] = a6;
    }
    __syncthreads();

    if (t == 0) {
        float s1 = 0.f, s2 = 0.f, s3 = 0.f, s4 = 0.f, s5 = 0.f, s6 = 0.f;
        #pragma unroll
        for (int w = 0; w < 4; ++w) {
            s1 += red[w][0]; s2 += red[w][1]; s3 += red[w][2];
            s4 += red[w][3]; s5 += red[w][4]; s6 += red[w][5];
        }
        const float total = s1 + s2 + s3 + s4 + s5 + s6;
        const float nq  = 1.0f + total;
        const float phi = (nq > 4.0f) ? (8.0f - 16.0f / nq) : nq;  // C=4,a=1
        const float c0  = 1.0f - phi;
        const bool  fin = isfinite(c0) && isfinite(total);

        float lo = 0.0f, hi = 2.0f;
        #pragma unroll 4
        for (int i = 0; i < NBISECT; ++i) {
            const float mid = 0.5f * (lo + hi);
            const float u = mid * mid;
            const float pv = ((((((s6*u + s5)*u + s4)*u + s3)*u + s2)*u + s1)*u) + c0;
            const bool neg = pv < 0.0f;               // NaN -> false (matches jnp.where)
            lo = neg ? mid : lo;
            hi = neg ? hi : mid;
        }
        float root = 0.5f * (lo + hi);
        if (!fin) root = 0.0f;
        root = fminf(root, 1.0f);

        const float inv = 1.0f / SAMP;
        float w1 = root, w2 = w1*root, w3 = w2*root, w4 = w3*root, w5 = w4*root, w6 = w5*root;
        float* dst = g_pw + (size_t)r * 6;
        dst[0] = w1 * inv; dst[1] = w2 * inv; dst[2] = w3 * inv;
        dst[3] = w4 * inv; dst[4] = w5 * inv; dst[5] = w6 * inv;
    }
}

// ---------------------------------------------------------------------------
// Phase 2: out[b,l] = sum_s x[b,s,l] * w[b,s][level(l)]  (1/32 pre-folded).
// Thread t owns cols [c0+4t, c0+4t+4): lane-adjacent float4 loads contiguous
// (1KB/wave/instr). Parity-split accumulator + shfl_up/LDS handoff (r4/r5
// proven). All hot loads NON-TEMPORAL (zero reuse). Batch order reversed.
// ---------------------------------------------------------------------------
__global__ __launch_bounds__(256, 5) void es_phase2_kernel(const float* __restrict__ x,
                                                           float* __restrict__ out) {
    const int bb = (BATCH - 1) - blockIdx.y;    // reversed batch index
    const int k  = blockIdx.x;
    const int t  = threadIdx.x;
    const int c0 = k * P2COLS;

    __shared__ float wsh[SAMP * 6];   // [s*6 + lev]
    __shared__ float xw[3][2];        // cross-wave handoff of ao2/ao3
    if (t < SAMP * 6) wsh[t] = g_pw[(size_t)bb * (SAMP * 6) + t];
    __syncthreads();

    const float* __restrict__ xb = x + (size_t)bb * (SAMP * (size_t)SIGLEN);

    if (c0 + P2COLS > SIGLEN) {                 // tail chunk: 74 cols, scalar
        const int col = c0 + t;
        if (col < SIGLEN) {
            const int lv = level0(col);
            float acc = 0.f;
            #pragma unroll 8
            for (int s = 0; s < SAMP; ++s)
                acc += xb[(size_t)s * SIGLEN + col] * wsh[s * 6 + lv];
            out[(size_t)bb * SIGLEN + col] = acc;
        }
        return;                                  // uniform for whole block
    }

    const int col = c0 + 4 * t;                  // multiple of 4
    // even rows (base%4==0): float4 at col    -> cols col..col+3
    // odd  rows (base%4==2): float4 at col+2  -> cols col+2..col+5 (16B-aligned)
    float ae0=0.f, ae1=0.f, ae2=0.f, ae3=0.f;    // even-parity partials, cols col+0..3
    float ao0=0.f, ao1=0.f, ao2=0.f, ao3=0.f;    // odd-parity partials, cols col+2..5
    float ah0=0.f, ah1=0.f;                      // t==0 only: odd partials, cols c0,c0+1

    const float* __restrict__ pe = xb + col;
    const float* __restrict__ po = xb + col + 2;

    const int lA = level0(col), lB = level0(col + 5);
    if (lA == lB) {                              // uniform level (all but ~6 threads/chunk)
        #pragma unroll
        for (int sp = 0; sp < 16; ++sp) {
            const int se = 2 * sp, so = 2 * sp + 1;
            const f32x4 ve = __builtin_nontemporal_load((const f32x4*)(pe + (size_t)se * SIGLEN));
            const f32x4 vo = __builtin_nontemporal_load((const f32x4*)(po + (size_t)so * SIGLEN));
            const float we = wsh[se * 6 + lA];
            const float wo = wsh[so * 6 + lA];
            ae0 += ve.x * we; ae1 += ve.y * we; ae2 += ve.z * we; ae3 += ve.w * we;
            ao0 += vo.x * wo; ao1 += vo.y * wo; ao2 += vo.z * wo; ao3 += vo.w * wo;
        }
    } else {                                     // level-boundary window: per-col weights
        const int le0 = level0(col),     le1 = level0(col + 1);
        const int le2 = level0(col + 2), le3 = level0(col + 3);
        const int lo2 = level0(col + 4), lo3 = level0(col + 5);
        #pragma unroll 4
        for (int sp = 0; sp < 16; ++sp) {
            const int se = 2 * sp, so = 2 * sp + 1;
            const f32x4 ve = __builtin_nontemporal_load((const f32x4*)(pe + (size_t)se * SIGLEN));
            const f32x4 vo = __builtin_nontemporal_load((const f32x4*)(po + (size_t)so * SIGLEN));
            ae0 += ve.x * wsh[se*6 + le0]; ae1 += ve.y * wsh[se*6 + le1];
            ae2 += ve.z * wsh[se*6 + le2]; ae3 += ve.w * wsh[se*6 + le3];
            ao0 += vo.x * wsh[so*6 + le2]; ao1 += vo.y * wsh[so*6 + le3];
            ao2 += vo.z * wsh[so*6 + lo2]; ao3 += vo.w * wsh[so*6 + lo3];
        }
    }

    if (t == 0) {                                // head: odd-parity cols c0, c0+1
        const int lh0 = level0(c0), lh1 = level0(c0 + 1);
        #pragma unroll
        for (int so = 1; so < SAMP; so += 2) {
            const f32x2 vh = __builtin_nontemporal_load(
                                 (const f32x2*)(xb + (size_t)so * SIGLEN + c0));
            ah0 += vh.x * wsh[so * 6 + lh0];
            ah1 += vh.y * wsh[so * 6 + lh1];
        }
    }

    // Realign odd partials: thread t's cols col,col+1 odd parts live in t-1's ao2,ao3.
    float po2 = __shfl_up(ao2, 1);               // valid within wave for lane>0
    float po3 = __shfl_up(ao3, 1);
    const int wave = t >> 6, lane = t & 63;
    if (lane == 63 && wave < 3) { xw[wave][0] = ao2; xw[wave][1] = ao3; }
    __syncthreads();
    if (lane == 0) {
        if (wave > 0) { po2 = xw[wave - 1][0]; po3 = xw[wave - 1][1]; }
        else          { po2 = ah0;             po3 = ah1;             }  // t==0
    }
    // (last thread's ao2/ao3 cover next chunk's first 2 cols -> discarded; that
    //  chunk's own head-float2 supplies them)

    const float f0 = ae0 + po2, f1 = ae1 + po3;
    const float f2 = ae2 + ao0, f3 = ae3 + ao1;

    float* op = out + (size_t)bb * SIGLEN + col; // elem base % 4 == 2*(bb&1)
    if ((bb & 1) == 0) {
        *(float4*)op = make_float4(f0, f1, f2, f3);
    } else {
        *(float2*)op       = make_float2(f0, f1);
        *(float2*)(op + 2) = make_float2(f2, f3);
    }
}

extern "C" void kernel_launch(void* const* d_in, const int* in_sizes, int n_in,
                              void* d_out, int out_size, void* d_ws, size_t ws_size,
                              hipStream_t stream) {
    const float* x = (const float*)d_in[0];   // [64,32,19530] fp32
    float* out = (float*)d_out;               // [64,19530] fp32
    (void)d_ws; (void)ws_size;                // workspace unused

    es_phase1_kernel<<<NROWS, 256, 0, stream>>>(x);
    dim3 gridB(P2GX, BATCH);
    es_phase2_kernel<<<gridB, 256, 0, stream>>>(x, out);
}